// Round 1
// baseline (536.629 us; speedup 1.0000x reference)
//
#include <hip/hip_runtime.h>

#define Bn 512
#define Tn 1024
#define Nn 64

__global__ __launch_bounds__(64) void crf_fwd(
    const float* __restrict__ emit,
    const int*   __restrict__ target,
    const int*   __restrict__ mask,
    const float* __restrict__ trans,
    const float* __restrict__ strans,
    const float* __restrict__ etrans,
    float*       __restrict__ out)
{
    __shared__ float  trans_lds[Nn * Nn];   // raw trans for score lookups
    __shared__ float4 pbuf4[2 * 16];        // p vector, double-buffered, 16B aligned
    __shared__ int    tbuf[2 * 64];         // staged targets, double-buffered chunks

    const int b    = blockIdx.x;
    const int lane = threadIdx.x;
    float* pbuf = (float*)pbuf4;

    // E column j in registers: Ecol[i] = exp(trans[i][j]) for j = lane.
    // Global read trans[i*64+lane] is coalesced per i.
    float Ecol[Nn];
#pragma unroll
    for (int i = 0; i < Nn; ++i) {
        float v = trans[i * Nn + lane];
        trans_lds[i * Nn + lane] = v;
        Ecol[i] = __expf(v);
    }

    // length = sum of prefix mask (mask passed as int32 0/1)
    const int* mrow = mask + (size_t)b * Tn;
    int lsum = 0;
#pragma unroll
    for (int k = 0; k < Tn / Nn; ++k) lsum += mrow[k * Nn + lane];
#pragma unroll
    for (int off = 32; off >= 1; off >>= 1) lsum += __shfl_xor(lsum, off, 64);
    const int len = lsum;   // in [512, 1024]

    const float strans_v = strans[lane];
    const float etrans_v = etrans[lane];
    const size_t ebase = (size_t)b * Tn * Nn;
    const int* trow = target + (size_t)b * Tn;

    // stage target chunk 0 (t = 0..63)
    tbuf[lane] = trow[lane];
    __syncthreads();

    // t = 0 init
    float emit0 = emit[ebase + lane];
    float alpha = strans_v + emit0;                 // alpha0 = strans + emit[b,0,:]
    int   tgt_prev = tbuf[0];
    float accL = (lane == tgt_prev) ? emit0 : 0.0f; // per-lane emit-score partial
    float accU = __shfl(strans_v, tgt_prev, 64);    // uniform score partial

    // emit prefetch ring: two 8-entry register buffers (all static indices)
    float ringA[8], ringB[8];
#pragma unroll
    for (int u = 0; u < 8; ++u) ringA[u] = emit[ebase + (size_t)(1 + u) * Nn + lane];
#pragma unroll
    for (int u = 0; u < 8; ++u) ringB[u] = emit[ebase + (size_t)(9 + u) * Nn + lane];

    auto step = [&](int t, float emit_cur) {
        // stage next 64 targets at chunk boundary (t multiple of 64; t <= 960)
        if ((t & 63) == 0)
            tbuf[((t >> 6) & 1) * 64 + lane] = trow[t + lane];

        // wave-uniform stabilizer: lane-0 alpha (exact algebraically; spread bounded)
        float m = __int_as_float(__builtin_amdgcn_readfirstlane(__float_as_int(alpha)));
        float p = __expf(alpha - m);
        int par = (t & 1) * 64;
        pbuf[par + lane] = p;
        __syncthreads();

        int tgt = tbuf[((t >> 6) & 1) * 64 + (t & 63)];

        // dot_j = sum_i p[i] * E[i][j]; p via broadcast b128 reads, E from VGPRs
        const float4* p4 = (const float4*)(pbuf + par);
        float a0 = 0.f, a1 = 0.f, a2 = 0.f, a3 = 0.f;
#pragma unroll
        for (int ib = 0; ib < 16; ++ib) {
            float4 pv = p4[ib];
            a0 = fmaf(pv.x, Ecol[4 * ib + 0], a0);
            a1 = fmaf(pv.y, Ecol[4 * ib + 1], a1);
            a2 = fmaf(pv.z, Ecol[4 * ib + 2], a2);
            a3 = fmaf(pv.w, Ecol[4 * ib + 3], a3);
        }
        float dot = (a0 + a1) + (a2 + a3);
        alpha = m + __logf(dot) + emit_cur;

        // score pieces
        accL += (lane == tgt) ? emit_cur : 0.0f;
        accU += trans_lds[tgt_prev * Nn + tgt];     // broadcast read
        tgt_prev = tgt;
    };

    int t = 1;
    while (t + 16 <= len) {
#pragma unroll
        for (int u = 0; u < 8; ++u) step(t + u, ringA[u]);
#pragma unroll
        for (int u = 0; u < 8; ++u) {
            int idx = t + 16 + u; if (idx >= len) idx = len - 1;
            ringA[u] = emit[ebase + (size_t)idx * Nn + lane];
        }
#pragma unroll
        for (int u = 0; u < 8; ++u) step(t + 8 + u, ringB[u]);
#pragma unroll
        for (int u = 0; u < 8; ++u) {
            int idx = t + 24 + u; if (idx >= len) idx = len - 1;
            ringB[u] = emit[ebase + (size_t)idx * Nn + lane];
        }
        t += 16;
    }
    // tail (< 16 steps): ringA = t..t+7, ringB = t+8..t+15 (clamped loads, valid slots correct)
#pragma unroll
    for (int u = 0; u < 16; ++u) {
        if (t + u < len) step(t + u, (u < 8) ? ringA[u] : ringB[u - 8]);
    }

    // end-transition score
    accU += __shfl(etrans_v, tgt_prev, 64);

    // logZ_b = logsumexp_j(alpha_j + etrans_j)
    float z = alpha + etrans_v;
    float m2 = z;
#pragma unroll
    for (int off = 32; off >= 1; off >>= 1) m2 = fmaxf(m2, __shfl_xor(m2, off, 64));
    float se = __expf(z - m2);
#pragma unroll
    for (int off = 32; off >= 1; off >>= 1) se += __shfl_xor(se, off, 64);
    float logZ = m2 + __logf(se);

    // reduce per-lane emit score
    float eL = accL;
#pragma unroll
    for (int off = 32; off >= 1; off >>= 1) eL += __shfl_xor(eL, off, 64);

    if (lane == 0) {
        atomicAdd(out, (logZ - (eL + accU)) * (1.0f / (float)Bn));
    }
}

extern "C" void kernel_launch(void* const* d_in, const int* in_sizes, int n_in,
                              void* d_out, int out_size, void* d_ws, size_t ws_size,
                              hipStream_t stream) {
    const float* emit   = (const float*)d_in[0];
    const int*   target = (const int*)d_in[1];
    const int*   mask   = (const int*)d_in[2];
    const float* trans  = (const float*)d_in[3];
    const float* strans = (const float*)d_in[4];
    const float* etrans = (const float*)d_in[5];
    float* out = (float*)d_out;

    hipMemsetAsync(out, 0, sizeof(float), stream);   // d_out is poisoned before each launch
    crf_fwd<<<Bn, Nn, 0, stream>>>(emit, target, mask, trans, strans, etrans, out);
}

// Round 2
// 386.221 us; speedup vs baseline: 1.3894x; 1.3894x over previous
//
#include <hip/hip_runtime.h>

#define Bn 512
#define Tn 1024
#define Nn 64

typedef _Float16 h2 __attribute__((ext_vector_type(2)));
typedef _Float16 h8 __attribute__((ext_vector_type(8)));

#if __has_builtin(__builtin_amdgcn_fdot2)
__device__ __forceinline__ float fdot2f(h2 a, h2 b, float c) {
    return __builtin_amdgcn_fdot2(a, b, c, false);
}
#else
__device__ __forceinline__ float fdot2f(h2 a, h2 b, float c) {
    return fmaf((float)a[0], (float)b[0], fmaf((float)a[1], (float)b[1], c));
}
#endif

// Single wave per block, one batch per wave. NO __syncthreads anywhere:
// same-wave LDS ops are processed in order by the DS pipe, and removing the
// barrier removes the implicit s_waitcnt vmcnt(0) drain that was serializing
// the emit prefetch ring (~100+ cyc/step in round 1).
__global__ __launch_bounds__(64) void crf_fwd(
    const float* __restrict__ emit,
    const int*   __restrict__ target,
    const int*   __restrict__ mask,
    const float* __restrict__ trans,
    const float* __restrict__ strans,
    const float* __restrict__ etrans,
    float*       __restrict__ out)
{
    __shared__ float trans_lds[Nn * Nn];                   // raw trans for score lookups
    __shared__ __align__(16) _Float16 pbuf[Nn];            // p vector, fp16
    __shared__ int tbuf[2 * 64];                           // staged targets

    const int b    = blockIdx.x;
    const int lane = threadIdx.x;

    // E column j (j = lane) as half2 pairs over i: E2[m] = {exp(T[2m][j]), exp(T[2m+1][j])}
    h2 E2[32];
#pragma unroll
    for (int m = 0; m < 32; ++m) {
        float x0 = trans[(2 * m) * Nn + lane];
        float x1 = trans[(2 * m + 1) * Nn + lane];
        trans_lds[(2 * m) * Nn + lane] = x0;
        trans_lds[(2 * m + 1) * Nn + lane] = x1;
        h2 e; e[0] = (_Float16)__expf(x0); e[1] = (_Float16)__expf(x1);
        E2[m] = e;
    }

    // len = popcount of prefix mask
    const int* mrow = mask + (size_t)b * Tn;
    int lsum = 0;
#pragma unroll
    for (int k = 0; k < Tn / Nn; ++k) lsum += mrow[k * Nn + lane];
#pragma unroll
    for (int off = 32; off >= 1; off >>= 1) lsum += __shfl_xor(lsum, off, 64);
    const int len = lsum;   // in [512, 1024]

    const float strans_v = strans[lane];
    const float etrans_v = etrans[lane];
    const size_t ebase = (size_t)b * Tn * Nn;
    const int* trow = target + (size_t)b * Tn;

    tbuf[lane] = trow[lane];            // chunk 0 (t = 0..63)

    // t = 0 init: alpha_0 = strans + e_0  ==  M(=0) + log(u) + e_0  with u = exp(strans)
    float e0 = emit[ebase + lane];
    float uu = __expf(strans_v);

    int   tgt_prev = tbuf[0];
    float accL = (lane == tgt_prev) ? e0 : 0.0f;   // per-lane emit-score partial
    float accU = __shfl(strans_v, tgt_prev, 64);   // uniform score partial

    double csum = 0.0;   // sum of per-step stabilizers c  (part of M)
    int    ksum = 0;     // sum of per-step pow2 rescales k (part of M)
    int    tstage = 0;

    // ---- prefetch pipeline warmup ----
    // eC: emit rows for steps t0..t0+7 ; eN: raw rows for next group
    float eC[8], eN[8], wC[8], cC;
#pragma unroll
    for (int q = 0; q < 8; ++q) eC[q] = emit[ebase + (size_t)(1 + q) * Nn + lane];
#pragma unroll
    for (int q = 0; q < 8; ++q) eN[q] = emit[ebase + (size_t)(9 + q) * Nn + lane];
    {
        // w,c for steps 1..8 (w of step t comes from emit row t-1: rows 0..7)
        float mm = e0;
#pragma unroll
        for (int q = 0; q < 7; ++q) mm = fmaxf(mm, eC[q]);
#pragma unroll
        for (int off = 32; off >= 1; off >>= 1) mm = fmaxf(mm, __shfl_xor(mm, off, 64));
        cC = mm;
        wC[0] = __expf(e0 - cC);
#pragma unroll
        for (int q = 0; q < 7; ++q) wC[q + 1] = __expf(eC[q] - cC);
    }

    // one recursion step: p_i = ldexp(u_i, -k) * w_i (fp16) ; u' = E^T p
    auto step = [&](int t, float w, float et) {
        // target chunk staging, split load(t-32)/write(t-16) to hide latency
        if (((t + 32) & 63) == 0) {
            int ti = t + 32 + lane; if (ti > Tn - 1) ti = Tn - 1;
            tstage = trow[ti];
        }
        if (((t + 16) & 63) == 0)
            tbuf[(((t + 16) >> 6) & 1) * 64 + lane] = tstage;

        // uniform pow2 rescale from lane-0 exponent bits (replaces per-step log)
        int bits = __builtin_amdgcn_readfirstlane(__float_as_int(uu));
        int mk   = 127 - ((bits >> 23) & 0xff);
        ksum    -= mk;                                  // k = -mk
        float p  = ldexpf(uu, mk) * w;                  // p in (0, ~5.4] -> fp16 safe
        pbuf[lane] = (_Float16)p;

        const h8* pb8 = (const h8*)pbuf;                // 8 broadcast b128 reads
        float a0 = 0.f, a1 = 0.f, a2 = 0.f, a3 = 0.f;
#pragma unroll
        for (int r = 0; r < 8; ++r) {
            h8 v = pb8[r];
            a0 = fdot2f(__builtin_shufflevector(v, v, 0, 1), E2[4 * r + 0], a0);
            a1 = fdot2f(__builtin_shufflevector(v, v, 2, 3), E2[4 * r + 1], a1);
            a2 = fdot2f(__builtin_shufflevector(v, v, 4, 5), E2[4 * r + 2], a2);
            a3 = fdot2f(__builtin_shufflevector(v, v, 6, 7), E2[4 * r + 3], a3);
        }
        uu = (a0 + a1) + (a2 + a3);

        // gold-path score pieces (off critical path)
        int tgt = tbuf[((t >> 6) & 1) * 64 + (t & 63)];
        accL += (lane == tgt) ? et : 0.0f;
        accU += trans_lds[tgt_prev * Nn + tgt];
        tgt_prev = tgt;
    };

    int t0 = 1;
    while (t0 + 8 <= len) {
#pragma unroll
        for (int q = 0; q < 8; ++q) step(t0 + q, wC[q], eC[q]);
        csum += 8.0 * (double)cC;

        // process next group's w/c: steps t0+8..t0+15 use emit rows t0+7..t0+14
        float mm = eC[7];
#pragma unroll
        for (int q = 0; q < 7; ++q) mm = fmaxf(mm, eN[q]);
#pragma unroll
        for (int off = 32; off >= 1; off >>= 1) mm = fmaxf(mm, __shfl_xor(mm, off, 64));
        float wN0 = __expf(eC[7] - mm);
        float wNr[7];
#pragma unroll
        for (int q = 0; q < 7; ++q) wNr[q] = __expf(eN[q] - mm);
        cC = mm;
        wC[0] = wN0;
#pragma unroll
        for (int q = 0; q < 7; ++q) wC[q + 1] = wNr[q];
#pragma unroll
        for (int q = 0; q < 8; ++q) eC[q] = eN[q];

        // issue raw loads for rows t0+16..t0+23 (consumed 2 groups later)
#pragma unroll
        for (int q = 0; q < 8; ++q) {
            int idx = t0 + 16 + q; if (idx >= len) idx = len - 1;
            eN[q] = emit[ebase + (size_t)idx * Nn + lane];
        }
        t0 += 8;
    }

    // tail: remaining steps t0..len-1 (0..7 of them)
    {
        int cnt = len - t0;
        csum += (double)cnt * (double)cC;
#pragma unroll
        for (int q = 0; q < 8; ++q)
            if (t0 + q < len) step(t0 + q, wC[q], eC[q]);
    }

    // finale: alpha_{len-1,j} = csum + ksum*ln2 + log(u_j) + e_{len-1,j}
    float eLst = emit[ebase + (size_t)(len - 1) * Nn + lane];
    float cl = eLst;
#pragma unroll
    for (int off = 32; off >= 1; off >>= 1) cl = fmaxf(cl, __shfl_xor(cl, off, 64));
    float zl = uu * __expf(eLst - cl) * __expf(etrans_v);
#pragma unroll
    for (int off = 32; off >= 1; off >>= 1) zl += __shfl_xor(zl, off, 64);

    accU += __shfl(etrans_v, tgt_prev, 64);
    float eLs = accL;
#pragma unroll
    for (int off = 32; off >= 1; off >>= 1) eLs += __shfl_xor(eLs, off, 64);

    float logZ = (float)csum + (float)ksum * 0.6931471805599453f + cl + __logf(zl);

    if (lane == 0)
        atomicAdd(out, (logZ - (eLs + accU)) * (1.0f / (float)Bn));
}

extern "C" void kernel_launch(void* const* d_in, const int* in_sizes, int n_in,
                              void* d_out, int out_size, void* d_ws, size_t ws_size,
                              hipStream_t stream) {
    const float* emit   = (const float*)d_in[0];
    const int*   target = (const int*)d_in[1];
    const int*   mask   = (const int*)d_in[2];
    const float* trans  = (const float*)d_in[3];
    const float* strans = (const float*)d_in[4];
    const float* etrans = (const float*)d_in[5];
    float* out = (float*)d_out;

    hipMemsetAsync(out, 0, sizeof(float), stream);
    crf_fwd<<<Bn, Nn, 0, stream>>>(emit, target, mask, trans, strans, etrans, out);
}

// Round 3
// 383.632 us; speedup vs baseline: 1.3988x; 1.0067x over previous
//
#include <hip/hip_runtime.h>

#define Bn 512
#define Tn 1024
#define Nn 64

typedef _Float16 h2 __attribute__((ext_vector_type(2)));
typedef _Float16 h8 __attribute__((ext_vector_type(8)));

#if __has_builtin(__builtin_amdgcn_fdot2)
__device__ __forceinline__ float fdot2f(h2 a, h2 b, float c) {
    return __builtin_amdgcn_fdot2(a, b, c, false);
}
#else
__device__ __forceinline__ float fdot2f(h2 a, h2 b, float c) {
    return fmaf((float)a[0], (float)b[0], fmaf((float)a[1], (float)b[1], c));
}
#endif

__device__ __forceinline__ float wave_sum(float v) {
#pragma unroll
    for (int off = 32; off >= 1; off >>= 1) v += __shfl_xor(v, off, 64);
    return v;
}

// One wave per block, one batch per wave. The step loop contains ONLY the
// forward recursion: p = u * 2^mk * w ; broadcast p via LDS ; u' = E^T p.
// No barriers, no score machinery, no stabilizer reductions in the loop.
// Scale tracking: exact per-step pow2 rescale (mk from lane-0 exponent bits),
// S = sum(mk); true alpha = log(u) - S*ln2 + emit_last.
__global__ __launch_bounds__(64) void crf_fused(
    const float* __restrict__ emit,
    const int*   __restrict__ target,
    const int*   __restrict__ mask,
    const float* __restrict__ trans,
    const float* __restrict__ strans,
    const float* __restrict__ etrans,
    float*       __restrict__ out)
{
    __shared__ __align__(16) _Float16 pbuf[Nn];

    const int b    = blockIdx.x;
    const int lane = threadIdx.x;

    // E column j (j = lane) as fp16 pairs over i: E2[m] = {exp(T[2m][j]), exp(T[2m+1][j])}
    h2 E2[32];
#pragma unroll
    for (int m = 0; m < 32; ++m) {
        float x0 = trans[(2 * m) * Nn + lane];
        float x1 = trans[(2 * m + 1) * Nn + lane];
        h2 e; e[0] = (_Float16)__expf(x0); e[1] = (_Float16)__expf(x1);
        E2[m] = e;
    }

    // len = popcount of prefix mask
    const int* mrow = mask + (size_t)b * Tn;
    int lsum = 0;
#pragma unroll
    for (int k = 0; k < Tn / Nn; ++k) lsum += mrow[k * Nn + lane];
#pragma unroll
    for (int off = 32; off >= 1; off >>= 1) lsum += __shfl_xor(lsum, off, 64);
    const int len = lsum;   // in [512, 1024]

    const size_t ebase = (size_t)b * Tn * Nn;

    // u_0 = exp(strans); w of emission row r = exp(emit[r]) enters step r+1.
    float uu = __expf(strans[lane]);
    int   S  = 0;           // sum of applied pow2 exponents

    // w pipeline: wC[q] = exp(emit row rb+q), rb = t0-1 ; eN = raw rows rb+8..rb+15
    float wC[8], eN[8];
#pragma unroll
    for (int q = 0; q < 8; ++q) wC[q] = emit[ebase + (size_t)q * Nn + lane];
#pragma unroll
    for (int q = 0; q < 8; ++q) eN[q] = emit[ebase + (size_t)(8 + q) * Nn + lane];
#pragma unroll
    for (int q = 0; q < 8; ++q) wC[q] = __expf(wC[q]);

    auto step = [&](float w) {
        // exact uniform pow2 rescale from lane-0 exponent bits
        int bits = __builtin_amdgcn_readfirstlane(__float_as_int(uu));
        int mk   = 127 - ((bits >> 23) & 0xff);
        S += mk;
        float p = ldexpf(uu, mk) * w;          // p in (0, ~1300) -> fp16 safe
        pbuf[lane] = (_Float16)p;

        const h8* pb8 = (const h8*)pbuf;       // 8 broadcast b128 reads (same-wave, in-order DS)
        float a0 = 0.f, a1 = 0.f, a2 = 0.f, a3 = 0.f;
        float a4 = 0.f, a5 = 0.f, a6 = 0.f, a7 = 0.f;
#pragma unroll
        for (int r = 0; r < 8; r += 2) {
            h8 v0 = pb8[r], v1 = pb8[r + 1];
            a0 = fdot2f(__builtin_shufflevector(v0, v0, 0, 1), E2[4 * r + 0], a0);
            a1 = fdot2f(__builtin_shufflevector(v0, v0, 2, 3), E2[4 * r + 1], a1);
            a2 = fdot2f(__builtin_shufflevector(v0, v0, 4, 5), E2[4 * r + 2], a2);
            a3 = fdot2f(__builtin_shufflevector(v0, v0, 6, 7), E2[4 * r + 3], a3);
            a4 = fdot2f(__builtin_shufflevector(v1, v1, 0, 1), E2[4 * r + 4], a4);
            a5 = fdot2f(__builtin_shufflevector(v1, v1, 2, 3), E2[4 * r + 5], a5);
            a6 = fdot2f(__builtin_shufflevector(v1, v1, 4, 5), E2[4 * r + 6], a6);
            a7 = fdot2f(__builtin_shufflevector(v1, v1, 6, 7), E2[4 * r + 7], a7);
        }
        uu = ((a0 + a1) + (a2 + a3)) + ((a4 + a5) + (a6 + a7));
    };

    int t0 = 1;
    while (t0 + 8 <= len) {
#pragma unroll
        for (int q = 0; q < 8; ++q) step(wC[q]);
        // advance w pipeline: next group's rows are exactly eN
#pragma unroll
        for (int q = 0; q < 8; ++q) wC[q] = __expf(eN[q]);
        // issue loads for rows (t0-1)+16 .. +23, consumed one boundary later
#pragma unroll
        for (int q = 0; q < 8; ++q) {
            int idx = t0 + 15 + q; if (idx > len - 1) idx = len - 1;
            eN[q] = emit[ebase + (size_t)idx * Nn + lane];
        }
        t0 += 8;
    }
    // tail: steps t0 .. len-1 (0..7 of them)
#pragma unroll
    for (int q = 0; q < 8; ++q)
        if (t0 + q < len) step(wC[q]);

    // ---- logZ epilogue ----
    float eL = emit[ebase + (size_t)(len - 1) * Nn + lane];
    float zl = wave_sum(uu * __expf(eL + etrans[lane]));
    float logZ = __logf(zl) - (float)S * 0.6931471805599453f;

    // ---- gold-path score epilogue (out of the hot loop entirely) ----
    const int* trow = target + (size_t)b * Tn;
    int tg[Tn / Nn], tp[Tn / Nn];
#pragma unroll
    for (int k = 0; k < Tn / Nn; ++k) tg[k] = trow[k * Nn + lane];
#pragma unroll
    for (int k = 0; k < Tn / Nn; ++k) {
        int t = k * Nn + lane;
        tp[k] = trow[t > 0 ? t - 1 : 0];
    }
    float sc = 0.0f;
#pragma unroll
    for (int k = 0; k < Tn / Nn; ++k) {
        int t = k * Nn + lane;
        if (t < len) {
            int g = tg[k];
            sc += emit[ebase + (size_t)t * Nn + g];           // scattered, L3-resident
            if (t > 0) sc += trans[tp[k] * Nn + g];           // 16 KB table, L1-resident
        }
    }
    sc = wave_sum(sc);

    if (lane == 0) {
        int g0 = trow[0];
        int gl = trow[len - 1];
        float score = sc + strans[g0] + etrans[gl];
        atomicAdd(out, (logZ - score) * (1.0f / (float)Bn));
    }
}

extern "C" void kernel_launch(void* const* d_in, const int* in_sizes, int n_in,
                              void* d_out, int out_size, void* d_ws, size_t ws_size,
                              hipStream_t stream) {
    const float* emit   = (const float*)d_in[0];
    const int*   target = (const int*)d_in[1];
    const int*   mask   = (const int*)d_in[2];
    const float* trans  = (const float*)d_in[3];
    const float* strans = (const float*)d_in[4];
    const float* etrans = (const float*)d_in[5];
    float* out = (float*)d_out;

    hipMemsetAsync(out, 0, sizeof(float), stream);
    crf_fused<<<Bn, Nn, 0, stream>>>(emit, target, mask, trans, strans, etrans, out);
}